// Round 1
// baseline (181.861 us; speedup 1.0000x reference)
//
#include <hip/hip_runtime.h>

// RelationAttention: B=8, S=512, H=256, A=64
//   ta = rh @ w_ta^T ; ja = rh @ w_ja^T            (B,S,A)
//   scores[b,i,j] = sum_a v[a]*tanh(ta[b,i,a]+ja[b,j,a]+bias[a])
//   out = softmax_j(scores)                        (B,S,S)
//
// Stage 1 writes ta2 = 2*(ta+bias)  (B,S,A)  and ja2 = 2*ja TRANSPOSED (B,A,S)
// so stage 2's inner global load (over j for fixed a) is coalesced.
// Stage 2 uses tanh(x) = 1 - 2/(1+exp(2x)):
//   score = sum(v) - sum_a (2*v[a]) * rcp(1 + exp(ta2 + ja2))

#define B_ 8
#define S_ 512
#define H_ 256
#define A_ 64

// ---------------- Stage 1: projections ----------------
// grid = 256 blocks (16 rows each), block = 128 threads.
// Thread t: col c = t&63 of BOTH w_ta and w_ja; rows (t>>6)*8 .. +7.
__global__ __launch_bounds__(128) void rel_stage1(
    const float* __restrict__ rh, const float* __restrict__ wta,
    const float* __restrict__ wja, const float* __restrict__ bias,
    float* __restrict__ ta2, float* __restrict__ ja2) {
  __shared__ __align__(16) float rhs[16][H_];  // 16 KB
  const int t = threadIdx.x;
  const int row0 = blockIdx.x << 4;
  {
    const float4* src = (const float4*)(rh + (size_t)row0 * H_);
    float4* dst = (float4*)&rhs[0][0];
#pragma unroll
    for (int i = 0; i < 8; ++i) dst[t + i * 128] = src[t + i * 128];
  }
  __syncthreads();
  const int c = t & 63;
  const int r8 = (t >> 6) << 3;  // 0 or 8
  const float* wt = wta + c * H_;
  const float* wj = wja + c * H_;
  float accT[8] = {0.f, 0.f, 0.f, 0.f, 0.f, 0.f, 0.f, 0.f};
  float accJ[8] = {0.f, 0.f, 0.f, 0.f, 0.f, 0.f, 0.f, 0.f};
#pragma unroll 2
  for (int k = 0; k < H_; k += 4) {
    const float4 a = *(const float4*)(wt + k);
    const float4 b = *(const float4*)(wj + k);
#pragma unroll
    for (int r = 0; r < 8; ++r) {
      const float4 x = *(const float4*)(&rhs[r8 + r][k]);  // broadcast b128
      accT[r] += a.x * x.x + a.y * x.y + a.z * x.z + a.w * x.w;
      accJ[r] += b.x * x.x + b.y * x.y + b.z * x.z + b.w * x.w;
    }
  }
  const float bb = 2.f * bias[c];
#pragma unroll
  for (int r = 0; r < 8; ++r) {
    const int row = row0 + r8 + r;
    ta2[(size_t)row * A_ + c] = 2.f * accT[r] + bb;     // coalesced over c
    const int bidx = row >> 9;                          // /S
    const int s = row & (S_ - 1);
    ja2[((size_t)bidx * A_ + c) * S_ + s] = 2.f * accJ[r];  // (B,A,S) transposed
  }
}

// ---------------- Stage 2: tanh-reduce + softmax ----------------
// grid = 1024 blocks (4 query rows each), block = 512 threads (thread = j).
__global__ __launch_bounds__(512) void rel_stage2(
    const float* __restrict__ ta2, const float* __restrict__ ja2,
    const float* __restrict__ v, float* __restrict__ out) {
  __shared__ __align__(16) float tai[4 * A_];  // 4 rows of ta2
  __shared__ __align__(16) float vv2[A_];      // 2*v
  __shared__ float red[4][8];
  const int t = threadIdx.x;
  const int row0 = blockIdx.x << 2;   // global row = b*S + i
  const int bidx = row0 >> 9;
  if (t < 4 * A_) tai[t] = ta2[(size_t)row0 * A_ + t];
  else if (t < 4 * A_ + A_) vv2[t - 4 * A_] = 2.f * v[t - 4 * A_];
  __syncthreads();

  float vsum = 0.f;
  {
    const float4* vp = (const float4*)vv2;
#pragma unroll
    for (int i = 0; i < A_ / 4; ++i) {
      const float4 x = vp[i];
      vsum += x.x + x.y + x.z + x.w;
    }
    vsum *= 0.5f;  // sum(v)
  }

  float acc0 = 0.f, acc1 = 0.f, acc2 = 0.f, acc3 = 0.f;
  const float* jp = ja2 + (size_t)bidx * A_ * S_ + t;
  auto term = [](float tv, float jv, float va) {
    return va * __builtin_amdgcn_rcpf(1.f + __expf(tv + jv));
  };
#pragma unroll
  for (int a4 = 0; a4 < A_; a4 += 4) {
    const float4 va4 = *(const float4*)&vv2[a4];
    const float4 t0 = *(const float4*)&tai[a4];
    const float4 t1 = *(const float4*)&tai[A_ + a4];
    const float4 t2 = *(const float4*)&tai[2 * A_ + a4];
    const float4 t3 = *(const float4*)&tai[3 * A_ + a4];
    float jv0 = jp[(size_t)(a4 + 0) * S_];  // coalesced: lanes j contiguous
    float jv1 = jp[(size_t)(a4 + 1) * S_];
    float jv2 = jp[(size_t)(a4 + 2) * S_];
    float jv3 = jp[(size_t)(a4 + 3) * S_];
    acc0 += term(t0.x, jv0, va4.x) + term(t0.y, jv1, va4.y) +
            term(t0.z, jv2, va4.z) + term(t0.w, jv3, va4.w);
    acc1 += term(t1.x, jv0, va4.x) + term(t1.y, jv1, va4.y) +
            term(t1.z, jv2, va4.z) + term(t1.w, jv3, va4.w);
    acc2 += term(t2.x, jv0, va4.x) + term(t2.y, jv1, va4.y) +
            term(t2.z, jv2, va4.z) + term(t2.w, jv3, va4.w);
    acc3 += term(t3.x, jv0, va4.x) + term(t3.y, jv1, va4.y) +
            term(t3.z, jv2, va4.z) + term(t3.w, jv3, va4.w);
  }
  float sc[4] = {vsum - acc0, vsum - acc1, vsum - acc2, vsum - acc3};

  // softmax over j (the 512 threads), per row r
  const int lane = t & 63;
  const int wv = t >> 6;
#pragma unroll
  for (int r = 0; r < 4; ++r) {
    float m = sc[r];
#pragma unroll
    for (int off = 32; off; off >>= 1) m = fmaxf(m, __shfl_xor(m, off));
    if (lane == 0) red[r][wv] = m;
  }
  __syncthreads();
  float mx[4];
#pragma unroll
  for (int r = 0; r < 4; ++r) {
    float m = red[r][0];
#pragma unroll
    for (int i = 1; i < 8; ++i) m = fmaxf(m, red[r][i]);
    mx[r] = m;
  }
  __syncthreads();
  float ex[4];
#pragma unroll
  for (int r = 0; r < 4; ++r) {
    ex[r] = __expf(sc[r] - mx[r]);
    float s = ex[r];
#pragma unroll
    for (int off = 32; off; off >>= 1) s += __shfl_xor(s, off);
    if (lane == 0) red[r][wv] = s;
  }
  __syncthreads();
#pragma unroll
  for (int r = 0; r < 4; ++r) {
    float s = 0.f;
#pragma unroll
    for (int i = 0; i < 8; ++i) s += red[r][i];
    out[(size_t)(row0 + r) * S_ + t] = ex[r] * __builtin_amdgcn_rcpf(s);
  }
}

extern "C" void kernel_launch(void* const* d_in, const int* in_sizes, int n_in,
                              void* d_out, int out_size, void* d_ws, size_t ws_size,
                              hipStream_t stream) {
  const float* rh   = (const float*)d_in[0];  // (B,S,H)
  const float* wta  = (const float*)d_in[1];  // (A,H)
  const float* wja  = (const float*)d_in[2];  // (A,H)
  const float* bias = (const float*)d_in[3];  // (1,1,1,A)
  const float* v    = (const float*)d_in[4];  // (1,A)
  float* out = (float*)d_out;                 // (B,S,S)

  float* ta2 = (float*)d_ws;                        // B*S*A floats = 1 MB
  float* ja2 = ta2 + (size_t)B_ * S_ * A_;          // B*A*S floats = 1 MB

  rel_stage1<<<dim3((B_ * S_) / 16), dim3(128), 0, stream>>>(rh, wta, wja, bias,
                                                             ta2, ja2);
  rel_stage2<<<dim3((B_ * S_) / 4), dim3(512), 0, stream>>>(ta2, ja2, v, out);
}

// Round 2
// 101.521 us; speedup vs baseline: 1.7914x; 1.7914x over previous
//
#include <hip/hip_runtime.h>

// RelationAttention: B=8, S=512, H=256, A=64
//   scores[b,i,j] = sum_a v[a]*tanh(ta[b,i,a]+ja[b,j,a]+b[a]); out = softmax_j
//
// tanh(x) = 1 - 2/(1+e^{2x});  e^{2(ta+b+ja)} = Et * Ej with
//   Et = exp(2*(ta+b))  stored (B,S,A)
//   Ej = exp(2*ja)      stored interleaved (B, A/4, S, 4) so stage-2's inner
//                       load is one coalesced float4 (4 a-values for lane's j)
// score = sum(v) - 2 * sum_a v[a] * rcp(1 + Et*Ej)
// Overflow-safe: Et*Ej -> inf => rcp->0 => tanh->1; ->0 => rcp(1)=1 => tanh->-1.

#define B_ 8
#define S_ 512
#define H_ 256
#define A_ 64

// ---------------- Stage 1: projections + exp precompute ----------------
// grid = 512 (64 row-blocks x 8 col-blocks of 16), block = 256 (4 waves).
// Thread: row = row0 + (t&63); wave w owns 4 consecutive cols (wave-uniform
// via readfirstlane -> w streamed through SGPRs, s_load, zero VMEM gathers).
__global__ __launch_bounds__(256) void rel_stage1(
    const float* __restrict__ rh, const float* __restrict__ wta,
    const float* __restrict__ wja, const float* __restrict__ bias,
    float* __restrict__ ta2e, float* __restrict__ ej) {
  __shared__ __align__(16) float rhs_s[64][68];  // +4 pad: float4-aligned
  const int t = threadIdx.x;
  const int cb = blockIdx.x & 7;   // col-block (16 cols)
  const int rb = blockIdx.x >> 3;  // row-block (64 rows)
  const int row0 = rb << 6;
  const int lane = t & 63;
  // combined col index 0..127 (0..63 -> w_ta, 64..127 -> w_ja), wave-uniform
  const int cgu = __builtin_amdgcn_readfirstlane(cb * 16 + ((t >> 6) << 2));
  const float* wbase = (cgu < A_) ? (wta + (size_t)cgu * H_)
                                  : (wja + (size_t)(cgu - A_) * H_);
  const float* w0 = wbase;
  const float* w1 = wbase + H_;
  const float* w2 = wbase + 2 * H_;
  const float* w3 = wbase + 3 * H_;

  float4 acc = {0.f, 0.f, 0.f, 0.f};
  for (int kt = 0; kt < H_; kt += 64) {
    __syncthreads();  // protect previous tile's readers
#pragma unroll
    for (int i = 0; i < 4; ++i) {
      const int fid = t + i * 256;
      const int r = fid >> 4, kq = fid & 15;
      *(float4*)&rhs_s[r][kq << 2] =
          *(const float4*)&rh[(size_t)(row0 + r) * H_ + kt + (kq << 2)];
    }
    __syncthreads();
#pragma unroll 4
    for (int kq = 0; kq < 16; ++kq) {
      const int kk = kt + (kq << 2);
      const float4 x = *(const float4*)&rhs_s[lane][kq << 2];
      acc.x += x.x * w0[kk] + x.y * w0[kk + 1] + x.z * w0[kk + 2] + x.w * w0[kk + 3];
      acc.y += x.x * w1[kk] + x.y * w1[kk + 1] + x.z * w1[kk + 2] + x.w * w1[kk + 3];
      acc.z += x.x * w2[kk] + x.y * w2[kk + 1] + x.z * w2[kk + 2] + x.w * w2[kk + 3];
      acc.w += x.x * w3[kk] + x.y * w3[kk + 1] + x.z * w3[kk + 2] + x.w * w3[kk + 3];
    }
  }

  const int row = row0 + lane;
  if (cgu < A_) {  // 'ta' columns: Et = exp(2*(ta + bias)), layout (B,S,A)
    float4 e;
    e.x = __expf(2.f * (acc.x + bias[cgu + 0]));
    e.y = __expf(2.f * (acc.y + bias[cgu + 1]));
    e.z = __expf(2.f * (acc.z + bias[cgu + 2]));
    e.w = __expf(2.f * (acc.w + bias[cgu + 3]));
    *(float4*)&ta2e[(size_t)row * A_ + cgu] = e;
  } else {  // 'ja' columns: Ej = exp(2*ja), layout (B, A/4, S, 4); coalesced b128
    const int a0 = cgu - A_;
    const int bidx = row >> 9;
    const int s = row & (S_ - 1);
    float4 e;
    e.x = __expf(2.f * acc.x);
    e.y = __expf(2.f * acc.y);
    e.z = __expf(2.f * acc.z);
    e.w = __expf(2.f * acc.w);
    *(float4*)&ej[((((size_t)bidx * 16 + (a0 >> 2)) * S_ + s) << 2)] = e;
  }
}

// ---------------- Stage 2: rcp-reduce + softmax ----------------
// grid = 1024 blocks (4 query rows each), block = 512 threads (thread = j).
// Et rows and v are block-uniform -> SGPR s_loads; only Ej is a vector load.
__global__ __launch_bounds__(512) void rel_stage2(
    const float* __restrict__ ta2e, const float* __restrict__ ej,
    const float* __restrict__ v, float* __restrict__ out) {
  __shared__ float red[4][8];
  const int t = threadIdx.x;
  const int row0 = blockIdx.x << 2;  // global row = b*S + i
  const int bidx = row0 >> 9;

  float vsum = 0.f;
#pragma unroll
  for (int a = 0; a < A_; a += 4) {  // uniform -> scalar loads
    const float4 vv = *(const float4*)&v[a];
    vsum += vv.x + vv.y + vv.z + vv.w;
  }

  float acc0 = 0.f, acc1 = 0.f, acc2 = 0.f, acc3 = 0.f;
  const float* ejb = ej + (((size_t)bidx * 16) * S_ << 2) + (t << 2);
#pragma unroll 2
  for (int g = 0; g < 16; ++g) {
    const float4 E = *(const float4*)(ejb + ((size_t)g * S_ << 2));
    const float4 V = *(const float4*)&v[g << 2];                    // SGPR
    const float4 T0 = *(const float4*)&ta2e[(size_t)(row0 + 0) * A_ + (g << 2)];
    const float4 T1 = *(const float4*)&ta2e[(size_t)(row0 + 1) * A_ + (g << 2)];
    const float4 T2 = *(const float4*)&ta2e[(size_t)(row0 + 2) * A_ + (g << 2)];
    const float4 T3 = *(const float4*)&ta2e[(size_t)(row0 + 3) * A_ + (g << 2)];
    acc0 += V.x * __builtin_amdgcn_rcpf(__builtin_fmaf(T0.x, E.x, 1.f))
          + V.y * __builtin_amdgcn_rcpf(__builtin_fmaf(T0.y, E.y, 1.f))
          + V.z * __builtin_amdgcn_rcpf(__builtin_fmaf(T0.z, E.z, 1.f))
          + V.w * __builtin_amdgcn_rcpf(__builtin_fmaf(T0.w, E.w, 1.f));
    acc1 += V.x * __builtin_amdgcn_rcpf(__builtin_fmaf(T1.x, E.x, 1.f))
          + V.y * __builtin_amdgcn_rcpf(__builtin_fmaf(T1.y, E.y, 1.f))
          + V.z * __builtin_amdgcn_rcpf(__builtin_fmaf(T1.z, E.z, 1.f))
          + V.w * __builtin_amdgcn_rcpf(__builtin_fmaf(T1.w, E.w, 1.f));
    acc2 += V.x * __builtin_amdgcn_rcpf(__builtin_fmaf(T2.x, E.x, 1.f))
          + V.y * __builtin_amdgcn_rcpf(__builtin_fmaf(T2.y, E.y, 1.f))
          + V.z * __builtin_amdgcn_rcpf(__builtin_fmaf(T2.z, E.z, 1.f))
          + V.w * __builtin_amdgcn_rcpf(__builtin_fmaf(T2.w, E.w, 1.f));
    acc3 += V.x * __builtin_amdgcn_rcpf(__builtin_fmaf(T3.x, E.x, 1.f))
          + V.y * __builtin_amdgcn_rcpf(__builtin_fmaf(T3.y, E.y, 1.f))
          + V.z * __builtin_amdgcn_rcpf(__builtin_fmaf(T3.z, E.z, 1.f))
          + V.w * __builtin_amdgcn_rcpf(__builtin_fmaf(T3.w, E.w, 1.f));
  }
  float sc[4] = {vsum - 2.f * acc0, vsum - 2.f * acc1, vsum - 2.f * acc2,
                 vsum - 2.f * acc3};

  // softmax over j (512 threads), per row r
  const int lane = t & 63;
  const int wv = t >> 6;
#pragma unroll
  for (int r = 0; r < 4; ++r) {
    float m = sc[r];
#pragma unroll
    for (int off = 32; off; off >>= 1) m = fmaxf(m, __shfl_xor(m, off));
    if (lane == 0) red[r][wv] = m;
  }
  __syncthreads();
  float mx[4];
#pragma unroll
  for (int r = 0; r < 4; ++r) {
    float m = red[r][0];
#pragma unroll
    for (int i = 1; i < 8; ++i) m = fmaxf(m, red[r][i]);
    mx[r] = m;
  }
  __syncthreads();
  float ex[4];
#pragma unroll
  for (int r = 0; r < 4; ++r) {
    ex[r] = __expf(sc[r] - mx[r]);
    float s = ex[r];
#pragma unroll
    for (int off = 32; off; off >>= 1) s += __shfl_xor(s, off);
    if (lane == 0) red[r][wv] = s;
  }
  __syncthreads();
#pragma unroll
  for (int r = 0; r < 4; ++r) {
    float s = 0.f;
#pragma unroll
    for (int i = 0; i < 8; ++i) s += red[r][i];
    out[(size_t)(row0 + r) * S_ + t] = ex[r] * __builtin_amdgcn_rcpf(s);
  }
}

extern "C" void kernel_launch(void* const* d_in, const int* in_sizes, int n_in,
                              void* d_out, int out_size, void* d_ws, size_t ws_size,
                              hipStream_t stream) {
  const float* rh   = (const float*)d_in[0];  // (B,S,H)
  const float* wta  = (const float*)d_in[1];  // (A,H)
  const float* wja  = (const float*)d_in[2];  // (A,H)
  const float* bias = (const float*)d_in[3];  // (1,1,1,A)
  const float* v    = (const float*)d_in[4];  // (1,A)
  float* out = (float*)d_out;                 // (B,S,S)

  float* ta2e = (float*)d_ws;                       // B*S*A floats = 1 MB
  float* ej   = ta2e + (size_t)B_ * S_ * A_;        // B*A*S floats = 1 MB

  rel_stage1<<<dim3(512), dim3(256), 0, stream>>>(rh, wta, wja, bias, ta2e, ej);
  rel_stage2<<<dim3((B_ * S_) / 4), dim3(512), 0, stream>>>(ta2e, ej, v, out);
}